// Round 18
// baseline (68.194 us; speedup 1.0000x reference)
//
#include <hip/hip_runtime.h>

// Problem constants (fixed by setup_inputs in the reference)
#define B_  8
#define N_  3072
#define C_  256
#define H_  128
#define W_  96
#define HW_ (H_ * W_)
#define NC_ (B_ * HW_)          // 98304 cells (~78% EMPTY: 0.25 tokens/cell)
#define NT_ (B_ * N_)           // 24576 tokens
#define EPSF 1e-6f

// Gaussian 3x3, sigma=2 (normalized): center, edge, corner
#define KW0 0.13080118f
#define KW1 0.11543166f
#define KW2 0.10186807f

// ws layout (u32 units). Proven ws_size ~= 384 MiB (harness poison WRITE_SIZE).
#define OFF_ASTART 0
#define OFF_ACUR   (NC_ + 1)
#define OFF_BSUM   (2 * NC_ + 1)
#define OFF_BOFF   (2 * NC_ + 1 + 384)
#define OFF_TOKS   (2 * NC_ + 1 + 768)
#define OFF_MEANS  (4 * 1024 * 1024)      // 16 MB in; NHWC bf16 means, NC_*512B = 50.3 MB
#define OFF_CNT8   (20 * 1024 * 1024)     // 80 MB in; NC_ bytes of u8 counts
// total reach ~80.1 MB << 384 MB

__device__ __forceinline__ unsigned f2bf(float f) {   // RNE f32->bf16 (low 16)
    const unsigned u = __float_as_uint(f);
    return (u + 0x7FFFu + ((u >> 16) & 1u)) >> 16;
}

// packed 2-wide f32 FMA (VOP3P, proven r17): d = a*b + c per half
__device__ __forceinline__ float2 pk_fma(float2 a, float2 b, float2 c) {
    float2 d;
    asm("v_pk_fma_f32 %0, %1, %2, %3" : "=v"(d) : "v"(a), "v"(b), "v"(c));
    return d;
}

// bf16x2 word -> float2 {even_ch, odd_ch}
__device__ __forceinline__ float2 unpk(unsigned w) {
    return make_float2(__uint_as_float(w << 16),
                       __uint_as_float(w & 0xFFFF0000u));
}

__device__ __forceinline__ void token_cell(const float* __restrict__ loc, int token,
                                           int& b, int& ix, int& iy) {
    b = token / N_;
    const float lx = fminf(fmaxf(loc[2 * token + 0], -1.0f), 1.0f);
    const float ly = fminf(fmaxf(loc[2 * token + 1], -1.0f), 1.0f);
    const float px = 0.5f * (lx + 1.0f) * (float)W_ - 0.5f;
    const float py = 0.5f * (ly + 1.0f) * (float)H_ - 0.5f;
    ix = (int)rintf(px); ix = min(max(ix, 0), W_ - 1);   // rintf = round-half-even = jnp.round
    iy = (int)rintf(py); iy = min(max(iy, 0), H_ - 1);
}

// Pass 1: histogram tokens into cells
__global__ void count_k(const float* __restrict__ loc, unsigned* __restrict__ cnts) {
    const int token = blockIdx.x * 256 + threadIdx.x;   // NT_ threads
    int b, ix, iy;
    token_cell(loc, token, b, ix, iy);
    atomicAdd(&cnts[b * HW_ + iy * W_ + ix], 1u);
}

// Pass 2a: per-block (256-cell) sums
__global__ void scanA(const unsigned* __restrict__ cnts, unsigned* __restrict__ Bsum) {
    const int i = blockIdx.x * 256 + threadIdx.x;
    int c = (int)cnts[i];
    #pragma unroll
    for (int off = 32; off > 0; off >>= 1) c += __shfl_down(c, off, 64);
    __shared__ int s[4];
    if ((threadIdx.x & 63) == 0) s[threadIdx.x >> 6] = c;
    __syncthreads();
    if (threadIdx.x == 0) Bsum[blockIdx.x] = (unsigned)(s[0] + s[1] + s[2] + s[3]);
}

// Pass 2b: exclusive scan of the 384 block sums (single block)
__global__ void scanB(const unsigned* __restrict__ Bsum, unsigned* __restrict__ Boff) {
    __shared__ unsigned s[512];
    const int t = threadIdx.x;
    const unsigned v = (t < 384) ? Bsum[t] : 0u;
    s[t] = v;
    __syncthreads();
    #pragma unroll
    for (int off = 1; off < 512; off <<= 1) {
        const unsigned a = (t >= off) ? s[t - off] : 0u;
        __syncthreads();
        s[t] += a;
        __syncthreads();
    }
    if (t < 384) Boff[t] = s[t] - v;   // exclusive
}

// Pass 2c: per-block exclusive scan + block offset -> Astart (and cursor copy)
__global__ void scanC(const unsigned* __restrict__ Boff,
                      unsigned* __restrict__ Astart, unsigned* __restrict__ Acur) {
    __shared__ unsigned s[256];
    const int t = threadIdx.x;
    const int i = blockIdx.x * 256 + t;
    const unsigned v = Acur[i];        // counts currently live in Acur
    s[t] = v;
    __syncthreads();
    #pragma unroll
    for (int off = 1; off < 256; off <<= 1) {
        const unsigned a = (t >= off) ? s[t - off] : 0u;
        __syncthreads();
        s[t] += a;
        __syncthreads();
    }
    const unsigned excl = s[t] - v + Boff[blockIdx.x];
    Astart[i] = excl;
    Acur[i]   = excl;                  // cursor starts at bin start
    if (i == 0) Astart[NC_] = NT_;     // total
}

// Pass 3: scatter token ids (packed with x) into bins
__global__ void fill_bins(const float* __restrict__ loc,
                          unsigned* __restrict__ Acur, unsigned* __restrict__ toks) {
    const int token = blockIdx.x * 256 + threadIdx.x;
    int b, ix, iy;
    token_cell(loc, token, b, ix, iy);
    const unsigned pos = atomicAdd(&Acur[b * HW_ + iy * W_ + ix], 1u);
    toks[pos] = ((unsigned)ix << 20) | (unsigned)token;
}

// Pass A: each (b,y) row walked EXACTLY ONCE. 4 waves x 24-cell quarter-rows;
// lane = channel-quad (float4 xf reads = 16B/lane). Writes NHWC bf16 means
// (coalesced 512B/cell) + u8 counts. Empty cells left unwritten (their means
// are never used: stencil coefs are 0; stale/poison bf16 is always finite).
__global__ __launch_bounds__(256) void gather_rows(const float* __restrict__ xf,
        const unsigned* __restrict__ Astart, const unsigned* __restrict__ toks,
        uint2* __restrict__ meansW, unsigned char* __restrict__ cnt8) {
    const int blk = (blockIdx.x & 7) * 128 + (blockIdx.x >> 3);   // b = blk>>7: one b per XCD
    const int b = blk >> 7, y = blk & 127;
    const int rowc = b * HW_ + y * W_;
    __shared__ unsigned rowptr[97];
    const int t = threadIdx.x;
    if (t < 97) rowptr[t] = Astart[rowc + t];
    __syncthreads();
    if (t < 96) {
        const unsigned c = rowptr[t + 1] - rowptr[t];
        cnt8[rowc + t] = (unsigned char)min(c, 255u);
    }
    const int wv = t >> 6, lane = t & 63;
    const unsigned p0 = rowptr[wv * 24], p1 = rowptr[wv * 24 + 24];
    int cur_x = -1;
    float4 acc = make_float4(0.f, 0.f, 0.f, 0.f);
    unsigned cnt = 0u;
    for (unsigned p = p0; p < p1; p += 4) {
        unsigned vv[4]; float4 ff[4];
        #pragma unroll
        for (int j = 0; j < 4; ++j)
            if (p + j < p1) vv[j] = toks[p + j];
        #pragma unroll
        for (int j = 0; j < 4; ++j)
            if (p + j < p1)
                ff[j] = *(const float4*)&xf[(size_t)(vv[j] & 0xFFFFFu) * C_ + lane * 4];
        #pragma unroll
        for (int j = 0; j < 4; ++j) {
            if (p + j >= p1) break;
            const int x = (int)(vv[j] >> 20);
            if (x != cur_x) {
                if (cur_x >= 0) {
                    const float rcp = 1.0f / ((float)cnt + EPSF);
                    uint2 o;
                    o.x = f2bf(acc.x * rcp) | (f2bf(acc.y * rcp) << 16);
                    o.y = f2bf(acc.z * rcp) | (f2bf(acc.w * rcp) << 16);
                    meansW[(size_t)(rowc + cur_x) * 64 + lane] = o;
                }
                acc = make_float4(0.f, 0.f, 0.f, 0.f); cnt = 0u; cur_x = x;
            }
            acc.x += ff[j].x; acc.y += ff[j].y;
            acc.z += ff[j].z; acc.w += ff[j].w;
            ++cnt;
        }
    }
    if (cur_x >= 0) {
        const float rcp = 1.0f / ((float)cnt + EPSF);
        uint2 o;
        o.x = f2bf(acc.x * rcp) | (f2bf(acc.y * rcp) << 16);
        o.y = f2bf(acc.z * rcp) | (f2bf(acc.w * rcp) << 16);
        meansW[(size_t)(rowc + cur_x) * 64 + lane] = o;
    }
}

// Pass B: pure stencil — NO data-dependent loads. Block = (b, y, 32-col
// x-tile, 128-ch half). Stage 3x34 cells' bf16 means from ws (independent
// streaming uint4 loads, L2-resident) + cflag bytes; per-thread 9-weight
// decode; pair-unpack + pk_fma blend; coalesced NCHW stores.
__global__ __launch_bounds__(256) void stencil_k(const uint4* __restrict__ meansW4,
        const unsigned char* __restrict__ cnt8, float* __restrict__ out) {
    const int blk = (blockIdx.x & 7) * 768 + (blockIdx.x >> 3);   // one b per XCD
    const int cg = blk & 1;
    int t2 = blk >> 1;
    const int xt = t2 % 3; t2 /= 3;
    const int y = t2 & 127, b = t2 >> 7;
    const int xs = xt * 32;

    __shared__ __align__(16) unsigned sm[3 * 34 * 68];   // 27744 B; col = 68 u32 (136 bf16, 16B-aligned stride)
    __shared__ unsigned char cflag[3][34];
    const int t = threadIdx.x;

    // cflag stage (102 threads)
    if (t < 102) {
        const int r = t / 34, xi = t - r * 34;
        const int yg = y - 1 + r, xg = xs - 1 + xi;
        unsigned char v = 0;
        if ((unsigned)yg < (unsigned)H_ && (unsigned)xg < (unsigned)W_)
            v = cnt8[b * HW_ + yg * W_ + xg] ? 1 : 0;
        cflag[r][xi] = v;
    }
    // sm stage: 3*34*17 = 1734 uint4 (k=16 is padding -> zero; OOB -> zero)
    uint4* sm4 = (uint4*)sm;
    for (int i = t; i < 1734; i += 256) {
        const int r = i / 578, rem = i - r * 578;
        const int col = rem / 17, k = rem - col * 17;
        const int yg = y - 1 + r, xg = xs - 1 + col;
        uint4 v = make_uint4(0u, 0u, 0u, 0u);
        if (k < 16 && (unsigned)yg < (unsigned)H_ && (unsigned)xg < (unsigned)W_)
            v = meansW4[(size_t)(b * HW_ + yg * W_ + xg) * 32 + cg * 16 + k];
        sm4[(r * 34 + col) * 17 + k] = v;
    }
    __syncthreads();

    // per-thread weights (fixed x column)
    const int xl = t & 31, sub = t >> 5;
    const int xi = xl + 1;
    float c9[9];
    {
        const float w0 = cflag[0][xi - 1] ? KW2 : 0.0f;
        const float w1 = cflag[0][xi]     ? KW1 : 0.0f;
        const float w2 = cflag[0][xi + 1] ? KW2 : 0.0f;
        const float w3 = cflag[1][xi - 1] ? KW1 : 0.0f;
        const float w5 = cflag[1][xi + 1] ? KW1 : 0.0f;
        const float w6 = cflag[2][xi - 1] ? KW2 : 0.0f;
        const float w7 = cflag[2][xi]     ? KW1 : 0.0f;
        const float w8 = cflag[2][xi + 1] ? KW2 : 0.0f;
        const bool ne  = cflag[1][xi] != 0;
        const float ms = ((w0 + w2) + (w6 + w8)) + ((w1 + w7) + (w3 + w5));
        const float inv = ne ? 0.0f : 1.0f / (ms + EPSF);   // ms==0 -> all 0
        c9[0] = w0 * inv; c9[1] = w1 * inv; c9[2] = w2 * inv;
        c9[3] = w3 * inv; c9[4] = ne ? 1.0f : 0.0f; c9[5] = w5 * inv;
        c9[6] = w6 * inv; c9[7] = w7 * inv; c9[8] = w8 * inv;
    }

    // blend 16 channels (sub*16..+15): 9 x {2 ds_read_b128 + pair-unpack + pk_fma}
    float2 acc[8];
    #pragma unroll
    for (int p = 0; p < 8; ++p) acc[p] = make_float2(0.f, 0.f);
    #pragma unroll
    for (int j = 0; j < 9; ++j) {
        const unsigned* basep = sm + ((j / 3) * 34 + (xi - 1 + j % 3)) * 68 + sub * 8;
        const uint4 w0 = *(const uint4*)basep;
        const uint4 w1 = *(const uint4*)(basep + 4);
        const float2 wp = make_float2(c9[j], c9[j]);
        acc[0] = pk_fma(unpk(w0.x), wp, acc[0]);
        acc[1] = pk_fma(unpk(w0.y), wp, acc[1]);
        acc[2] = pk_fma(unpk(w0.z), wp, acc[2]);
        acc[3] = pk_fma(unpk(w0.w), wp, acc[3]);
        acc[4] = pk_fma(unpk(w1.x), wp, acc[4]);
        acc[5] = pk_fma(unpk(w1.y), wp, acc[5]);
        acc[6] = pk_fma(unpk(w1.z), wp, acc[6]);
        acc[7] = pk_fma(unpk(w1.w), wp, acc[7]);
    }
    float* op = out + ((size_t)(b * C_ + cg * 128 + sub * 16)) * HW_
                    + (size_t)y * W_ + xs + xl;
    #pragma unroll
    for (int p = 0; p < 8; ++p) {
        op[(size_t)(2 * p)     * HW_] = acc[p].x;
        op[(size_t)(2 * p + 1) * HW_] = acc[p].y;
    }
}

extern "C" void kernel_launch(void* const* d_in, const int* in_sizes, int n_in,
                              void* d_out, int out_size, void* d_ws, size_t ws_size,
                              hipStream_t stream) {
    const float* x   = (const float*)d_in[0];   // (B, N, C) f32
    const float* loc = (const float*)d_in[1];   // (B, N, 2) f32
    float* out = (float*)d_out;                 // (B, C, H, W) f32

    unsigned* W32 = (unsigned*)d_ws;
    unsigned* Astart = W32 + OFF_ASTART;
    unsigned* Acur   = W32 + OFF_ACUR;
    unsigned* Bsum   = W32 + OFF_BSUM;
    unsigned* Boff   = W32 + OFF_BOFF;
    unsigned* toks   = W32 + OFF_TOKS;
    uint2*    meansW = (uint2*)(W32 + OFF_MEANS);
    unsigned char* cnt8 = (unsigned char*)(W32 + OFF_CNT8);

    hipMemsetAsync(Acur, 0, (size_t)NC_ * sizeof(unsigned), stream);

    count_k  <<<NT_ / 256, 256, 0, stream>>>(loc, Acur);
    scanA    <<<NC_ / 256, 256, 0, stream>>>(Acur, Bsum);
    scanB    <<<1, 512, 0, stream>>>(Bsum, Boff);
    scanC    <<<NC_ / 256, 256, 0, stream>>>(Boff, Astart, Acur);
    fill_bins<<<NT_ / 256, 256, 0, stream>>>(loc, Acur, toks);

    gather_rows<<<B_ * H_, 256, 0, stream>>>(x, Astart, toks, meansW, cnt8);
    stencil_k<<<B_ * H_ * 3 * 2, 256, 0, stream>>>((const uint4*)meansW, cnt8, out);
}

// Round 19
// 57.033 us; speedup vs baseline: 1.1957x; 1.1957x over previous
//
#include <hip/hip_runtime.h>

// Problem constants (fixed by setup_inputs in the reference)
#define B_  8
#define N_  3072
#define C_  256
#define H_  128
#define W_  96
#define HW_ (H_ * W_)
#define NC_ (B_ * HW_)          // 98304 cells (~78% EMPTY: 0.25 tokens/cell)
#define NT_ (B_ * N_)           // 24576 tokens
#define EPSF 1e-6f

// Gaussian 3x3, sigma=2 (normalized): center, edge, corner
#define KW0 0.13080118f
#define KW1 0.11543166f
#define KW2 0.10186807f

// fused-kernel tiling: block = (b, 2-row pair, 32-col x-tile, 128-ch group)
#define CG_ 128                 // channels per block (lane covers 2 via float2)
#define XT_ 32                  // x columns written per block
#define XS_ 34                  // staged columns (32 + 2 halo)
#define CPB 132                 // bf16 channel pad (row = 264 B; breaks pow2 banks)
#define RY_ 2                   // output rows per block (4 staged rows, 1 per wave)
#define NWG_ (B_ * (H_ / RY_) * 3 * 2)   // 3072 blocks; 3072 % 8 == 0

// ws layout (u32 units) — round-4-proven layout (ws is actually ~384 MB).
#define OFF_ASTART 0
#define OFF_ACUR   (NC_ + 1)
#define OFF_BSUM   (2 * NC_ + 1)
#define OFF_BOFF   (2 * NC_ + 1 + 384)
#define OFF_TOKS   (2 * NC_ + 1 + 768)

__device__ __forceinline__ unsigned f2bf(float f) {   // RNE f32->bf16 (low 16)
    const unsigned u = __float_as_uint(f);
    return (u + 0x7FFFu + ((u >> 16) & 1u)) >> 16;
}

// packed 2-wide f32 FMA (VOP3P, mechanism proven r17/r18): d = a*b + c per half
__device__ __forceinline__ float2 pk_fma(float2 a, float2 b, float2 c) {
    float2 d;
    asm("v_pk_fma_f32 %0, %1, %2, %3" : "=v"(d) : "v"(a), "v"(b), "v"(c));
    return d;
}

// bf16x2 word -> float2 {even_ch, odd_ch}
__device__ __forceinline__ float2 unpk(unsigned w) {
    return make_float2(__uint_as_float(w << 16),
                       __uint_as_float(w & 0xFFFF0000u));
}

__device__ __forceinline__ void token_cell(const float* __restrict__ loc, int token,
                                           int& b, int& ix, int& iy) {
    b = token / N_;
    const float lx = fminf(fmaxf(loc[2 * token + 0], -1.0f), 1.0f);
    const float ly = fminf(fmaxf(loc[2 * token + 1], -1.0f), 1.0f);
    const float px = 0.5f * (lx + 1.0f) * (float)W_ - 0.5f;
    const float py = 0.5f * (ly + 1.0f) * (float)H_ - 0.5f;
    ix = (int)rintf(px); ix = min(max(ix, 0), W_ - 1);   // rintf = round-half-even = jnp.round
    iy = (int)rintf(py); iy = min(max(iy, 0), H_ - 1);
}

// Pass 1: histogram tokens into cells
__global__ void count_k(const float* __restrict__ loc, unsigned* __restrict__ cnts) {
    const int token = blockIdx.x * 256 + threadIdx.x;   // NT_ threads
    int b, ix, iy;
    token_cell(loc, token, b, ix, iy);
    atomicAdd(&cnts[b * HW_ + iy * W_ + ix], 1u);
}

// Pass 2a: per-block (256-cell) sums
__global__ void scanA(const unsigned* __restrict__ cnts, unsigned* __restrict__ Bsum) {
    const int i = blockIdx.x * 256 + threadIdx.x;
    int c = (int)cnts[i];
    #pragma unroll
    for (int off = 32; off > 0; off >>= 1) c += __shfl_down(c, off, 64);
    __shared__ int s[4];
    if ((threadIdx.x & 63) == 0) s[threadIdx.x >> 6] = c;
    __syncthreads();
    if (threadIdx.x == 0) Bsum[blockIdx.x] = (unsigned)(s[0] + s[1] + s[2] + s[3]);
}

// Pass 2b: exclusive scan of the 384 block sums (single block)
__global__ void scanB(const unsigned* __restrict__ Bsum, unsigned* __restrict__ Boff) {
    __shared__ unsigned s[512];
    const int t = threadIdx.x;
    const unsigned v = (t < 384) ? Bsum[t] : 0u;
    s[t] = v;
    __syncthreads();
    #pragma unroll
    for (int off = 1; off < 512; off <<= 1) {
        const unsigned a = (t >= off) ? s[t - off] : 0u;
        __syncthreads();
        s[t] += a;
        __syncthreads();
    }
    if (t < 384) Boff[t] = s[t] - v;   // exclusive
}

// Pass 2c: per-block exclusive scan + block offset -> Astart (and cursor copy)
__global__ void scanC(const unsigned* __restrict__ Boff,
                      unsigned* __restrict__ Astart, unsigned* __restrict__ Acur) {
    __shared__ unsigned s[256];
    const int t = threadIdx.x;
    const int i = blockIdx.x * 256 + t;
    const unsigned v = Acur[i];        // counts currently live in Acur
    s[t] = v;
    __syncthreads();
    #pragma unroll
    for (int off = 1; off < 256; off <<= 1) {
        const unsigned a = (t >= off) ? s[t - off] : 0u;
        __syncthreads();
        s[t] += a;
        __syncthreads();
    }
    const unsigned excl = s[t] - v + Boff[blockIdx.x];
    Astart[i] = excl;
    Acur[i]   = excl;                  // cursor starts at bin start
    if (i == 0) Astart[NC_] = NT_;     // total
}

// Pass 3: scatter token ids (packed with x) into bins
__global__ void fill_bins(const float* __restrict__ loc,
                          unsigned* __restrict__ Acur, unsigned* __restrict__ toks) {
    const int token = blockIdx.x * 256 + threadIdx.x;
    int b, ix, iy;
    token_cell(loc, token, b, ix, iy);
    const unsigned pos = atomicAdd(&Acur[b * HW_ + iy * W_ + ix], 1u);
    toks[pos] = ((unsigned)ix << 20) | (unsigned)token;
}

// Pass 4 (FUSED, 2 rows/block, branchless pk_fma fill, XCD-swizzled):
//   identical to the round-16 best except the fill inner loop uses
//   pair-unpack + v_pk_fma_f32 (halves FMA issue; same LDS load pattern).
__global__ __launch_bounds__(256) void fused_k(const float* __restrict__ xf,
        const unsigned* __restrict__ Astart, const unsigned* __restrict__ toks,
        float* __restrict__ out) {
    // XCD-aware swizzle: each XCD's 384-block chunk covers exactly one b.
    const int blk = (blockIdx.x & 7) * (NWG_ / 8) + (blockIdx.x >> 3);
    const int cg = blk & 1;              // ((b*64 + yp)*3 + xt)*2 + cg
    const int t2 = blk >> 1;
    const int xt = t2 % 3;
    const int t3 = t2 / 3;
    const int yp = t3 & 63;
    const int b  = t3 >> 6;
    const int y0 = yp * RY_;
    const int xs = xt * XT_;
    const int lane = threadIdx.x & 63;
    const int wv = threadIdx.x >> 6;

    __shared__ __align__(16) unsigned short means[4 * XS_ * CPB];   // 35904 B
    __shared__ unsigned long long cmask[4];
    __shared__ float coef[RY_][XT_][10];                            // 2560 B

    // (1) per-wave Astart stage for row y0-1+wv (issues early; latency
    //     overlaps the zero-init below). OOB rows -> cmask 0, empty range.
    const int yg = y0 - 1 + wv;
    const bool inrow = ((unsigned)yg < (unsigned)H_);
    unsigned p0, p1;
    {
        unsigned a = 0u;
        if (inrow && lane < XS_ + 1) {
            int g = xs - 1 + lane;                 // [xs-1, xs+33]
            g = min(max(g, 0), W_);                // Astart[..+W_] = row end
            a = Astart[b * HW_ + yg * W_ + g];
        }
        const unsigned an = __shfl_down(a, 1, 64);
        const unsigned long long mask = __ballot(lane < XS_ && an > a);
        if (lane == 0) cmask[wv] = mask;
        p0 = __shfl(a, 0, 64);
        p1 = __shfl(a, XS_, 64);
    }

    // (2) zero-init means (bf16 +0.0 = 0x0000); empty cells stay exactly 0
    {
        uint4* p4 = (uint4*)means;
        for (int i = threadIdx.x; i < 4 * XS_ * CPB / 8; i += 256)
            p4[i] = make_uint4(0u, 0u, 0u, 0u);
    }
    __syncthreads();   // A: init + cmask ready

    // (3a) wave 0: per-cell coefficient table (64 cells = 2 rows x 32 x)
    if (wv == 0) {
        const int r  = lane >> 5;
        const int xl = lane & 31;
        const int xi = xl + 1;
        const unsigned long long cm0 = cmask[r], cm1 = cmask[r + 1],
                                 cm2 = cmask[r + 2];
        const float w0 = ((cm0 >> (xi - 1)) & 1ULL) ? KW2 : 0.0f;
        const float w1 = ((cm0 >> xi)       & 1ULL) ? KW1 : 0.0f;
        const float w2 = ((cm0 >> (xi + 1)) & 1ULL) ? KW2 : 0.0f;
        const float w3 = ((cm1 >> (xi - 1)) & 1ULL) ? KW1 : 0.0f;
        const float w5 = ((cm1 >> (xi + 1)) & 1ULL) ? KW1 : 0.0f;
        const float w6 = ((cm2 >> (xi - 1)) & 1ULL) ? KW2 : 0.0f;
        const float w7 = ((cm2 >> xi)       & 1ULL) ? KW1 : 0.0f;
        const float w8 = ((cm2 >> (xi + 1)) & 1ULL) ? KW2 : 0.0f;
        const bool ne  = (cm1 >> xi) & 1ULL;
        const float ms = ((w0 + w2) + (w6 + w8)) + ((w1 + w7) + (w3 + w5));
        const float inv = ne ? 0.0f : 1.0f / (ms + EPSF);   // ms==0 -> all 0
        coef[r][xl][0] = w0 * inv;
        coef[r][xl][1] = w1 * inv;
        coef[r][xl][2] = w2 * inv;
        coef[r][xl][3] = w3 * inv;
        coef[r][xl][4] = ne ? 1.0f : 0.0f;   // self (nonempty copy)
        coef[r][xl][5] = w5 * inv;
        coef[r][xl][6] = w6 * inv;
        coef[r][xl][7] = w7 * inv;
        coef[r][xl][8] = w8 * inv;
    }

    // (3b) all waves: batch-4 contiguous CSR walk of [p0,p1) into slot wv
    if (inrow) {
        unsigned* msw = (unsigned*)(means + wv * XS_ * CPB);   // u32 view
        int cur_xi = -1;
        float acc0 = 0.0f, acc1 = 0.0f;
        unsigned cnt = 0u;
        for (unsigned p = p0; p < p1; p += 4) {
            unsigned vv[4]; float2 ff[4];
            #pragma unroll
            for (int j = 0; j < 4; ++j)
                if (p + j < p1) vv[j] = toks[p + j];
            #pragma unroll
            for (int j = 0; j < 4; ++j)
                if (p + j < p1)
                    ff[j] = *(const float2*)&xf[(size_t)(vv[j] & 0xFFFFFu) * C_
                                                + cg * CG_ + 2 * lane];
            #pragma unroll
            for (int j = 0; j < 4; ++j) {
                if (p + j >= p1) break;
                const int xi = (int)(vv[j] >> 20) - xs + 1;   // in [0, 34)
                if (xi != cur_xi) {
                    if (cur_xi >= 0) {
                        const float rcp = 1.0f / ((float)cnt + EPSF);
                        msw[cur_xi * (CPB / 2) + lane] =
                            f2bf(acc0 * rcp) | (f2bf(acc1 * rcp) << 16);
                    }
                    acc0 = acc1 = 0.0f; cnt = 0u; cur_xi = xi;
                }
                acc0 += ff[j].x; acc1 += ff[j].y; ++cnt;
            }
        }
        if (cur_xi >= 0) {
            const float rcp = 1.0f / ((float)cnt + EPSF);
            msw[cur_xi * (CPB / 2) + lane] = f2bf(acc0 * rcp) | (f2bf(acc1 * rcp) << 16);
        }
    }
    __syncthreads();   // B: means + coef ready

    // (4) fill: thread = fixed x (xl) x 16 channels x 2 rows; branchless
    //     9-term blend via uint2 LDS reads + pair-unpack + v_pk_fma_f32.
    const int xl  = threadIdx.x & 31;
    const int sub = threadIdx.x >> 5;
    const int xi  = xl + 1;
    const int c0  = sub * 16;

    #pragma unroll
    for (int r = 0; r < RY_; ++r) {
        float c9[9];
        #pragma unroll
        for (int j = 0; j < 9; ++j) c9[j] = coef[r][xl][j];

        float2 acc[8];
        #pragma unroll
        for (int p = 0; p < 8; ++p) acc[p] = make_float2(0.f, 0.f);

        #pragma unroll
        for (int j = 0; j < 9; ++j) {
            const int slot = r + j / 3;
            const int col  = xi - 1 + j % 3;
            // byte offset = (slot*XS_+col)*264 + c0*2  -> 8B-aligned (c0 mult of 16)
            const uint2* b2 = (const uint2*)(means + (slot * XS_ + col) * CPB + c0);
            const float2 wp = make_float2(c9[j], c9[j]);
            #pragma unroll
            for (int p = 0; p < 4; ++p) {
                const uint2 w = b2[p];          // channels c0+4p .. c0+4p+3
                acc[2 * p]     = pk_fma(unpk(w.x), wp, acc[2 * p]);
                acc[2 * p + 1] = pk_fma(unpk(w.y), wp, acc[2 * p + 1]);
            }
        }
        float* op = out + ((size_t)(b * C_ + cg * CG_ + c0)) * HW_
                        + (size_t)(y0 + r) * W_ + xs + xl;
        #pragma unroll
        for (int p = 0; p < 8; ++p) {
            op[(size_t)(2 * p)     * HW_] = acc[p].x;
            op[(size_t)(2 * p + 1) * HW_] = acc[p].y;
        }
    }
}

extern "C" void kernel_launch(void* const* d_in, const int* in_sizes, int n_in,
                              void* d_out, int out_size, void* d_ws, size_t ws_size,
                              hipStream_t stream) {
    const float* x   = (const float*)d_in[0];   // (B, N, C) f32
    const float* loc = (const float*)d_in[1];   // (B, N, 2) f32
    float* out = (float*)d_out;                 // (B, C, H, W) f32

    unsigned* W32 = (unsigned*)d_ws;
    unsigned* Astart = W32 + OFF_ASTART;
    unsigned* Acur   = W32 + OFF_ACUR;
    unsigned* Bsum   = W32 + OFF_BSUM;
    unsigned* Boff   = W32 + OFF_BOFF;
    unsigned* toks   = W32 + OFF_TOKS;

    hipMemsetAsync(Acur, 0, (size_t)NC_ * sizeof(unsigned), stream);

    count_k  <<<NT_ / 256, 256, 0, stream>>>(loc, Acur);
    scanA    <<<NC_ / 256, 256, 0, stream>>>(Acur, Bsum);
    scanB    <<<1, 512, 0, stream>>>(Bsum, Boff);
    scanC    <<<NC_ / 256, 256, 0, stream>>>(Boff, Astart, Acur);
    fill_bins<<<NT_ / 256, 256, 0, stream>>>(loc, Acur, toks);

    // grid = 3072 blocks (XCD-swizzled inside the kernel)
    fused_k<<<NWG_, 256, 0, stream>>>(x, Astart, toks, out);
}